// Round 1
// baseline (885.435 us; speedup 1.0000x reference)
//
#include <hip/hip_runtime.h>

#define Nn 32
#define Cc 64
#define Vv 25
#define Tt 1024

typedef __attribute__((ext_vector_type(4))) float f32x4;
typedef __attribute__((ext_vector_type(8))) short bf16x8;

__device__ __forceinline__ unsigned short f2bf(float f) {
    union { float f; unsigned u; } a; a.f = f;
    unsigned u = a.u;
    u += 0x7fff + ((u >> 16) & 1);   // RNE
    return (unsigned short)(u >> 16);
}

// Kernel 1: Weff[v][w][c][c'] (bf16) = sum_k A[k][w][v] * W[w][c*3+k][c']
__global__ __launch_bounds__(256) void weff_prep(
        const float* __restrict__ W, const float* __restrict__ A,
        unsigned short* __restrict__ Weff) {
    int v = blockIdx.x / Vv;
    int w = blockIdx.x - v * Vv;
    float a0 = A[(0 * Vv + w) * Vv + v];
    float a1 = A[(1 * Vv + w) * Vv + v];
    float a2 = A[(2 * Vv + w) * Vv + v];
    const float* Wb = W + (size_t)w * 192 * 64;
    unsigned short* o = Weff + (size_t)(v * Vv + w) * 4096;
    int e0 = threadIdx.x * 16;
    #pragma unroll
    for (int i = 0; i < 16; ++i) {
        int e = e0 + i;
        int c = e >> 6, cp = e & 63;
        float val = a0 * Wb[(c * 3 + 0) * 64 + cp]
                  + a1 * Wb[(c * 3 + 1) * 64 + cp]
                  + a2 * Wb[(c * 3 + 2) * 64 + cp];
        o[e] = f2bf(val);
    }
}

// Kernel 2: out[n, 0:64, v, t0:t0+256] = sum_w Weff[v,w] (64x64) @ x[n,:,w,t0:t0+256]
// Block: 256 threads = 4 waves; wave wv computes 64(c) x 64(t) via 4x4 mfma_16x16x32_bf16 tiles.
__global__ __launch_bounds__(256, 2) void gc_main(
        const float* __restrict__ x, const unsigned short* __restrict__ Weff,
        float* __restrict__ out) {
    // LDS: x tile transposed [t=256][c'=64] stride 72, Weff tile [c=64][c'=64] stride 72
    __shared__ __align__(16) unsigned short xs[256 * 72];
    __shared__ __align__(16) unsigned short wa[64 * 72];

    // XCD-aware swizzle: 3200 blocks = 8 XCD * 400; per XCD: 16 slices x 25 v,
    // v-minor within 2 v-groups (13 + 12) so x-slice + Weff-group stay L2-resident.
    int bid = blockIdx.x;
    int xcd = bid & 7;
    int lid = bid >> 3;            // 0..399
    int v, s;
    if (lid < 13 * 16) { v = lid % 13;            s = lid / 13; }
    else { int l2 = lid - 13 * 16; v = 13 + l2 % 12; s = l2 / 12; }
    int slice = (xcd << 4) + s;    // 0..127
    int n  = slice >> 2;           // 0..31
    int t0 = (slice & 3) << 8;     // 0,256,512,768

    int tid  = threadIdx.x;
    int lane = tid & 63;
    int wv   = tid >> 6;           // wave id 0..3
    int m    = lane & 15;
    int quad = lane >> 4;

    int cc = tid & 7;              // c' block (8 blocks of 8)
    int tt = tid >> 3;             // 0..31  (t = tt*4+j  and  128+tt*4+j)

    f32x4 acc[4][4];
    #pragma unroll
    for (int i = 0; i < 4; ++i)
        #pragma unroll
        for (int j = 0; j < 4; ++j)
            acc[i][j] = (f32x4){0.f, 0.f, 0.f, 0.f};

    const float* xg = x + (size_t)n * Cc * Vv * Tt + t0 + tt * 4;
    const bf16x8* wg = (const bf16x8*)(Weff + (size_t)v * Vv * 4096);

    for (int w = 0; w < Vv; ++w) {
        if (w) __syncthreads();
        // ---- stage Weff tile (v,w): 4096 bf16 = 512 x 16B chunks ----
        #pragma unroll
        for (int r = 0; r < 2; ++r) {
            int q = r * 256 + tid;          // 0..511
            int c = q >> 3, b = q & 7;
            *(bf16x8*)&wa[c * 72 + b * 8] = wg[w * 512 + q];
        }
        // ---- stage x tile (n,w,t0): 64 c' x 256 t fp32 -> bf16, transposed to [t][c'] ----
        {
            bf16x8 rows[8];
            #pragma unroll
            for (int i = 0; i < 8; ++i) {
                int cp = cc * 8 + i;
                const float* p = xg + ((size_t)cp * Vv + w) * Tt;
                float4 f0 = *(const float4*)p;          // t = tt*4 .. +3
                float4 f1 = *(const float4*)(p + 128);  // t = 128 + tt*4 .. +3
                rows[0][i] = (short)f2bf(f0.x); rows[1][i] = (short)f2bf(f0.y);
                rows[2][i] = (short)f2bf(f0.z); rows[3][i] = (short)f2bf(f0.w);
                rows[4][i] = (short)f2bf(f1.x); rows[5][i] = (short)f2bf(f1.y);
                rows[6][i] = (short)f2bf(f1.z); rows[7][i] = (short)f2bf(f1.w);
            }
            #pragma unroll
            for (int j = 0; j < 4; ++j) {
                *(bf16x8*)&xs[(tt * 4 + j) * 72 + cc * 8]         = rows[j];
                *(bf16x8*)&xs[(128 + tt * 4 + j) * 72 + cc * 8]   = rows[4 + j];
            }
        }
        __syncthreads();
        // ---- compute: K=64 as 2 chunks of 32 ----
        #pragma unroll
        for (int kc = 0; kc < 2; ++kc) {
            int ko = kc * 32 + quad * 8;
            bf16x8 afr[4], bfr[4];
            #pragma unroll
            for (int mi = 0; mi < 4; ++mi)
                afr[mi] = *(const bf16x8*)&wa[(mi * 16 + m) * 72 + ko];
            #pragma unroll
            for (int ni = 0; ni < 4; ++ni)
                bfr[ni] = *(const bf16x8*)&xs[(wv * 64 + ni * 16 + m) * 72 + ko];
            #pragma unroll
            for (int mi = 0; mi < 4; ++mi)
                #pragma unroll
                for (int ni = 0; ni < 4; ++ni)
                    acc[mi][ni] = __builtin_amdgcn_mfma_f32_16x16x32_bf16(
                        afr[mi], bfr[ni], acc[mi][ni], 0, 0, 0);
        }
    }

    // ---- epilogue: D layout col(t)=lane&15, row(c)=quad*4+reg ----
    float* og = out + ((size_t)n * Cc * Vv + v) * Tt + t0 + wv * 64 + m;
    #pragma unroll
    for (int mi = 0; mi < 4; ++mi)
        #pragma unroll
        for (int r = 0; r < 4; ++r) {
            int c = mi * 16 + quad * 4 + r;
            float* orow = og + (size_t)c * Vv * Tt;
            #pragma unroll
            for (int ni = 0; ni < 4; ++ni)
                orow[ni * 16] = acc[mi][ni][r];
        }
}

extern "C" void kernel_launch(void* const* d_in, const int* in_sizes, int n_in,
                              void* d_out, int out_size, void* d_ws, size_t ws_size,
                              hipStream_t stream) {
    const float* x = (const float*)d_in[0];   // [32,64,25,1024]
    const float* W = (const float*)d_in[1];   // [25,192,64]
    const float* A = (const float*)d_in[2];   // [3,25,25]
    float* out = (float*)d_out;               // [32,64,25,1024]
    unsigned short* Weff = (unsigned short*)d_ws;  // 2.56M bf16 = 5.12 MB

    weff_prep<<<dim3(Vv * Vv), dim3(256), 0, stream>>>(W, A, Weff);
    gc_main<<<dim3(3200), dim3(256), 0, stream>>>(x, Weff, out);
}

// Round 2
// 667.216 us; speedup vs baseline: 1.3271x; 1.3271x over previous
//
#include <hip/hip_runtime.h>

#define Nn 32
#define Cc 64
#define Vv 25
#define Tt 1024

typedef __attribute__((ext_vector_type(4))) float f32x4;
typedef __attribute__((ext_vector_type(8))) short bf16x8;
typedef __attribute__((ext_vector_type(4))) unsigned short u16x4;

__device__ __forceinline__ unsigned short f2bf(float f) {
    union { float f; unsigned u; } a; a.f = f;
    unsigned u = a.u;
    u += 0x7fff + ((u >> 16) & 1);   // RNE
    return (unsigned short)(u >> 16);
}

// ---------------- fast path ----------------

// Weff[v][w] tile (64c x 64c') bf16, XOR-swizzled: within a 128B row c,
// logical 16B chunk jl stored at physical chunk jl^(c&7).
__global__ __launch_bounds__(256) void weff_prep_sw(
        const float* __restrict__ W, const float* __restrict__ A,
        unsigned short* __restrict__ Weff) {
    int v = blockIdx.x / Vv;
    int w = blockIdx.x - v * Vv;
    float a0 = A[(0 * Vv + w) * Vv + v];
    float a1 = A[(1 * Vv + w) * Vv + v];
    float a2 = A[(2 * Vv + w) * Vv + v];
    const float* Wb = W + (size_t)w * 192 * 64;
    unsigned short* o = Weff + (size_t)(v * Vv + w) * 4096;
    int c  = threadIdx.x >> 2;
    int c0 = (threadIdx.x & 3) * 16;
    #pragma unroll
    for (int i = 0; i < 16; ++i) {
        int cp = c0 + i;
        float val = a0 * Wb[(c * 3 + 0) * 64 + cp]
                  + a1 * Wb[(c * 3 + 1) * 64 + cp]
                  + a2 * Wb[(c * 3 + 2) * 64 + cp];
        int jl = cp >> 3;
        o[c * 64 + ((jl ^ (c & 7)) << 3) + (cp & 7)] = f2bf(val);
    }
}

// x[n][c'][w][t] fp32 -> xb[n][w][t][c'] bf16, same XOR swizzle per 128B t-row.
// Block = (n, w, 64-t tile): LDS transpose.
__global__ __launch_bounds__(256) void x_convert(
        const float* __restrict__ x, unsigned short* __restrict__ xb) {
    __shared__ __align__(16) unsigned short tile[64 * 64];
    int bid = blockIdx.x;
    int n = bid / (Vv * 16);
    int rem = bid - n * (Vv * 16);
    int w = rem >> 4;
    int t0 = (rem & 15) << 6;
    int tid = threadIdx.x;
    int g = tid & 15, q = tid >> 4;
    const float* xp = x + ((size_t)(n * Cc) * Vv + w) * Tt + t0 + q * 4;
    f32x4 f[4];
    #pragma unroll
    for (int cj = 0; cj < 4; ++cj)
        f[cj] = *(const f32x4*)(xp + (size_t)(g * 4 + cj) * Vv * Tt);
    #pragma unroll
    for (int r = 0; r < 4; ++r) {
        int t = q * 4 + r;
        u16x4 h = { f2bf(f[0][r]), f2bf(f[1][r]), f2bf(f[2][r]), f2bf(f[3][r]) };
        int pc = (g >> 1) ^ (t & 7);
        *(u16x4*)&tile[t * 64 + pc * 8 + (g & 1) * 4] = h;
    }
    __syncthreads();
    unsigned short* dst = xb + ((size_t)(n * Vv + w) * Tt + t0) * 64;
    #pragma unroll
    for (int r = 0; r < 2; ++r) {
        int fo = tid * 16 + r * 8;
        *(bf16x8*)&dst[fo] = *(const bf16x8*)&tile[fo];
    }
}

// out[n, 0:64, v, t0:t0+256] = sum_w Weff[v,w] @ xb[n,w,t0:t0+256,:]
// B fragments direct global->reg; only Weff staged in LDS (8KB, dbuf via regs).
__global__ __launch_bounds__(256) void gc_fast(
        const unsigned short* __restrict__ xb,
        const unsigned short* __restrict__ Weff,
        float* __restrict__ out) {
    __shared__ __align__(16) unsigned short wa[2][64 * 64];

    int bid = blockIdx.x;                 // 3200 = 8 xcd * (16 slices * 25 v), v fastest
    int xcd = bid & 7;
    int lid = bid >> 3;
    int v = lid % Vv;
    int s = lid / Vv;                     // 0..15
    int slice = (xcd << 4) + s;           // 0..127
    int n  = slice >> 2;
    int t0 = (slice & 3) << 8;

    int tid = threadIdx.x;
    int lane = tid & 63, wv = tid >> 6;
    int m = lane & 15, quad = lane >> 4;

    const unsigned short* wg = Weff + (size_t)v * (Vv * 4096);
    const unsigned short* xbase = xb + ((size_t)(n * Vv) * Tt + t0) * 64;

    int coff0 = ((quad)     ^ (m & 7)) << 3;   // kc=0 chunk offset (swizzled)
    int coff1 = ((4 + quad) ^ (m & 7)) << 3;   // kc=1
    int trow[4], arow[4];
    #pragma unroll
    for (int ni = 0; ni < 4; ++ni) trow[ni] = (wv * 64 + ni * 16 + m) * 64;
    #pragma unroll
    for (int mi = 0; mi < 4; ++mi) arow[mi] = (mi * 16 + m) * 64;

    // stage w=0 A tile
    {
        bf16x8 p0 = ((const bf16x8*)wg)[tid];
        bf16x8 p1 = ((const bf16x8*)wg)[tid + 256];
        ((bf16x8*)wa[0])[tid] = p0;
        ((bf16x8*)wa[0])[tid + 256] = p1;
    }

    f32x4 acc[4][4];
    #pragma unroll
    for (int i = 0; i < 4; ++i)
        #pragma unroll
        for (int j = 0; j < 4; ++j)
            acc[i][j] = (f32x4){0.f, 0.f, 0.f, 0.f};

    for (int w = 0; w < Vv; ++w) {
        __syncthreads();
        const unsigned short* cur = wa[w & 1];
        const unsigned short* xw = xbase + (size_t)w * (Tt * 64);
        // B fragments: direct global loads (L2-hot)
        bf16x8 b0[4], b1[4];
        #pragma unroll
        for (int ni = 0; ni < 4; ++ni) {
            b0[ni] = *(const bf16x8*)(xw + trow[ni] + coff0);
            b1[ni] = *(const bf16x8*)(xw + trow[ni] + coff1);
        }
        // prefetch next A tile into regs (written to other LDS buf after compute)
        bf16x8 q0, q1;
        if (w < Vv - 1) {
            const bf16x8* wn = (const bf16x8*)(wg + (size_t)(w + 1) * 4096);
            q0 = wn[tid]; q1 = wn[tid + 256];
        }
        // A fragments from LDS
        bf16x8 a0[4], a1[4];
        #pragma unroll
        for (int mi = 0; mi < 4; ++mi) {
            a0[mi] = *(const bf16x8*)(cur + arow[mi] + coff0);
            a1[mi] = *(const bf16x8*)(cur + arow[mi] + coff1);
        }
        #pragma unroll
        for (int mi = 0; mi < 4; ++mi)
            #pragma unroll
            for (int ni = 0; ni < 4; ++ni)
                acc[mi][ni] = __builtin_amdgcn_mfma_f32_16x16x32_bf16(
                    a0[mi], b0[ni], acc[mi][ni], 0, 0, 0);
        #pragma unroll
        for (int mi = 0; mi < 4; ++mi)
            #pragma unroll
            for (int ni = 0; ni < 4; ++ni)
                acc[mi][ni] = __builtin_amdgcn_mfma_f32_16x16x32_bf16(
                    a1[mi], b1[ni], acc[mi][ni], 0, 0, 0);
        if (w < Vv - 1) {
            unsigned short* nxt = wa[(w + 1) & 1];
            ((bf16x8*)nxt)[tid] = q0;
            ((bf16x8*)nxt)[tid + 256] = q1;
        }
    }

    // epilogue: D layout col(t)=lane&15, row(c)=quad*4+reg  (verified in R1)
    float* og = out + ((size_t)n * Cc * Vv + v) * Tt + t0 + wv * 64 + m;
    #pragma unroll
    for (int mi = 0; mi < 4; ++mi)
        #pragma unroll
        for (int r = 0; r < 4; ++r) {
            int c = mi * 16 + quad * 4 + r;
            float* orow = og + (size_t)c * Vv * Tt;
            #pragma unroll
            for (int ni = 0; ni < 4; ++ni)
                orow[ni * 16] = acc[mi][ni][r];
        }
}

// ---------------- fallback path (R1, proven) ----------------

__global__ __launch_bounds__(256) void weff_prep_plain(
        const float* __restrict__ W, const float* __restrict__ A,
        unsigned short* __restrict__ Weff) {
    int v = blockIdx.x / Vv;
    int w = blockIdx.x - v * Vv;
    float a0 = A[(0 * Vv + w) * Vv + v];
    float a1 = A[(1 * Vv + w) * Vv + v];
    float a2 = A[(2 * Vv + w) * Vv + v];
    const float* Wb = W + (size_t)w * 192 * 64;
    unsigned short* o = Weff + (size_t)(v * Vv + w) * 4096;
    int e0 = threadIdx.x * 16;
    #pragma unroll
    for (int i = 0; i < 16; ++i) {
        int e = e0 + i;
        int c = e >> 6, cp = e & 63;
        float val = a0 * Wb[(c * 3 + 0) * 64 + cp]
                  + a1 * Wb[(c * 3 + 1) * 64 + cp]
                  + a2 * Wb[(c * 3 + 2) * 64 + cp];
        o[e] = f2bf(val);
    }
}

__global__ __launch_bounds__(256, 2) void gc_plain(
        const float* __restrict__ x, const unsigned short* __restrict__ Weff,
        float* __restrict__ out) {
    __shared__ __align__(16) unsigned short xs[256 * 72];
    __shared__ __align__(16) unsigned short wa[64 * 72];
    int bid = blockIdx.x;
    int xcd = bid & 7;
    int lid = bid >> 3;
    int v, s;
    if (lid < 13 * 16) { v = lid % 13;            s = lid / 13; }
    else { int l2 = lid - 13 * 16; v = 13 + l2 % 12; s = l2 / 12; }
    int slice = (xcd << 4) + s;
    int n  = slice >> 2;
    int t0 = (slice & 3) << 8;
    int tid  = threadIdx.x;
    int lane = tid & 63;
    int wv   = tid >> 6;
    int m    = lane & 15;
    int quad = lane >> 4;
    int cc = tid & 7;
    int tt = tid >> 3;
    f32x4 acc[4][4];
    #pragma unroll
    for (int i = 0; i < 4; ++i)
        #pragma unroll
        for (int j = 0; j < 4; ++j)
            acc[i][j] = (f32x4){0.f, 0.f, 0.f, 0.f};
    const float* xg = x + (size_t)n * Cc * Vv * Tt + t0 + tt * 4;
    const bf16x8* wg = (const bf16x8*)(Weff + (size_t)v * Vv * 4096);
    for (int w = 0; w < Vv; ++w) {
        if (w) __syncthreads();
        #pragma unroll
        for (int r = 0; r < 2; ++r) {
            int q = r * 256 + tid;
            int c = q >> 3, b = q & 7;
            *(bf16x8*)&wa[c * 72 + b * 8] = wg[w * 512 + q];
        }
        {
            bf16x8 rows[8];
            #pragma unroll
            for (int i = 0; i < 8; ++i) {
                int cp = cc * 8 + i;
                const float* p = xg + ((size_t)cp * Vv + w) * Tt;
                float4 f0 = *(const float4*)p;
                float4 f1 = *(const float4*)(p + 128);
                rows[0][i] = (short)f2bf(f0.x); rows[1][i] = (short)f2bf(f0.y);
                rows[2][i] = (short)f2bf(f0.z); rows[3][i] = (short)f2bf(f0.w);
                rows[4][i] = (short)f2bf(f1.x); rows[5][i] = (short)f2bf(f1.y);
                rows[6][i] = (short)f2bf(f1.z); rows[7][i] = (short)f2bf(f1.w);
            }
            #pragma unroll
            for (int j = 0; j < 4; ++j) {
                *(bf16x8*)&xs[(tt * 4 + j) * 72 + cc * 8]       = rows[j];
                *(bf16x8*)&xs[(128 + tt * 4 + j) * 72 + cc * 8] = rows[4 + j];
            }
        }
        __syncthreads();
        #pragma unroll
        for (int kc = 0; kc < 2; ++kc) {
            int ko = kc * 32 + quad * 8;
            bf16x8 afr[4], bfr[4];
            #pragma unroll
            for (int mi = 0; mi < 4; ++mi)
                afr[mi] = *(const bf16x8*)&wa[(mi * 16 + m) * 72 + ko];
            #pragma unroll
            for (int ni = 0; ni < 4; ++ni)
                bfr[ni] = *(const bf16x8*)&xs[(wv * 64 + ni * 16 + m) * 72 + ko];
            #pragma unroll
            for (int mi = 0; mi < 4; ++mi)
                #pragma unroll
                for (int ni = 0; ni < 4; ++ni)
                    acc[mi][ni] = __builtin_amdgcn_mfma_f32_16x16x32_bf16(
                        afr[mi], bfr[ni], acc[mi][ni], 0, 0, 0);
        }
    }
    float* og = out + ((size_t)n * Cc * Vv + v) * Tt + t0 + wv * 64 + m;
    #pragma unroll
    for (int mi = 0; mi < 4; ++mi)
        #pragma unroll
        for (int r = 0; r < 4; ++r) {
            int c = mi * 16 + quad * 4 + r;
            float* orow = og + (size_t)c * Vv * Tt;
            #pragma unroll
            for (int ni = 0; ni < 4; ++ni)
                orow[ni * 16] = acc[mi][ni][r];
        }
}

extern "C" void kernel_launch(void* const* d_in, const int* in_sizes, int n_in,
                              void* d_out, int out_size, void* d_ws, size_t ws_size,
                              hipStream_t stream) {
    const float* x = (const float*)d_in[0];   // [32,64,25,1024]
    const float* W = (const float*)d_in[1];   // [25,192,64]
    const float* A = (const float*)d_in[2];   // [3,25,25]
    float* out = (float*)d_out;

    const size_t xb_elems   = (size_t)Nn * Vv * Tt * 64;       // 52,428,800
    const size_t weff_elems = (size_t)Vv * Vv * 4096;          //  2,560,000
    const size_t need = (xb_elems + weff_elems) * sizeof(unsigned short);

    if (ws_size >= need) {
        unsigned short* xb   = (unsigned short*)d_ws;
        unsigned short* Weff = xb + xb_elems;
        weff_prep_sw<<<dim3(Vv * Vv), dim3(256), 0, stream>>>(W, A, Weff);
        x_convert<<<dim3(Nn * Vv * 16), dim3(256), 0, stream>>>(x, xb);
        gc_fast<<<dim3(3200), dim3(256), 0, stream>>>(xb, Weff, out);
    } else {
        unsigned short* Weff = (unsigned short*)d_ws;
        weff_prep_plain<<<dim3(Vv * Vv), dim3(256), 0, stream>>>(W, A, Weff);
        gc_plain<<<dim3(3200), dim3(256), 0, stream>>>(x, Weff, out);
    }
}